// Round 5
// baseline (107.608 us; speedup 1.0000x reference)
//
#include <hip/hip_runtime.h>
#include <hip/hip_bf16.h>

#define B_   64
#define NL_  128
#define NP_  128
#define E_   4096

// ---------------------------------------------------------------------------
// Math: num[b] = <Q, R>,  Q = P[b]@A,  R = W[b]@P[b],
//       W[b][i][j] = sum of w_e over edges e=(i,j) of batch b.
//       den[b] = sum_e w_e;  loss = -(1/B) sum_b num[b]/max(den[b],1e-8)
//
// ws layout (bytes):
//   [0, 4194304)       Wt f32 [B][j=128][i=128]  (W transposed, global atomics)
//   [4194304, +256)    den[64]                    (atomics)
//   [4194560, +2048)   num_part[512]
//   [4196608, +65536)  A f32 [128][128]
// memset zeroes [0, 4194560) (Wt + den) each call.
// ---------------------------------------------------------------------------

// K1: A-chunk build + den partial + edge scatter into global Wt.
// 128 blocks = 64 batches x 2 halves (2048 edges each).
__global__ __launch_bounds__(256) void k_prep(
    const float* __restrict__ d_error,
    const int*   __restrict__ d_hw,
    const float* __restrict__ ew,
    const int*   __restrict__ pairs_raw,
    float* __restrict__ A,
    float* __restrict__ Wt,
    float* __restrict__ den)
{
    const int blk  = blockIdx.x;
    const int b    = blk >> 1;
    const int half = blk & 1;
    const int t    = threadIdx.x;

    // A: 128 elements per block (16384 total over 128 blocks)
    if (t < 128) {
        int idx = blk * 128 + t;
        A[idx] = (d_hw[idx] == 1) ? fmaxf(1.0f - d_error[idx], 0.0f) : 0.0f;
    }

    // int64-vs-int32 detection: high words of first 64 values all zero <=> int64
    int hwv = pairs_raw[2 * (t & 63) + 1];
    unsigned long long nz = __ballot(hwv != 0);
    const int is64 = (nz == 0ULL);

    const float* wrow = ew + (size_t)b * E_ + half * 2048;

    // den partial: 2048 weights
    {
        const float4* ew4 = (const float4*)wrow;
        float4 v0 = ew4[t];
        float4 v1 = ew4[t + 256];
        float s = v0.x + v0.y + v0.z + v0.w + v1.x + v1.y + v1.z + v1.w;
        #pragma unroll
        for (int off = 32; off >= 1; off >>= 1) s += __shfl_xor(s, off, 64);
        __shared__ float rs[4];
        if ((t & 63) == 0) rs[t >> 6] = s;
        __syncthreads();
        if (t == 0) atomicAdd(&den[b], rs[0] + rs[1] + rs[2] + rs[3]);
    }

    // edge scatter: Wt[b][j][i] += w   (2048 edges per block)
    float* Wb = Wt + (size_t)b * (NL_ * NL_);
    if (is64) {
        const int4* pp = (const int4*)pairs_raw + (size_t)b * E_ + half * 2048;
        #pragma unroll 4
        for (int k = 0; k < 8; ++k) {
            int e = k * 256 + t;
            int4 pr = pp[e];
            atomicAdd(&Wb[pr.z * NL_ + pr.x], wrow[e]);
        }
    } else {
        const int2* pp = (const int2*)pairs_raw + (size_t)b * E_ + half * 2048;
        #pragma unroll 4
        for (int k = 0; k < 8; ++k) {
            int e = k * 256 + t;
            int2 pr = pp[e];
            atomicAdd(&Wb[pr.y * NL_ + pr.x], wrow[e]);
        }
    }
}

// K2: LDS-free. 512 blocks = 64 batches x 8 row-chunks; 256 threads.
// Thread: rows r0+2tr, r0+2tr+1 (local), cols 4tc..4tc+3.
__global__ __launch_bounds__(256) void k_main(
    const float* __restrict__ P,
    const float* __restrict__ A,
    const float* __restrict__ Wt,
    float* __restrict__ num_part)
{
    const int b     = blockIdx.x >> 3;
    const int chunk = blockIdx.x & 7;
    const int r0    = chunk * 16;
    const int t  = threadIdx.x;
    const int tr = t >> 5;
    const int tc = t & 31;

    const float* Pb  = P + (size_t)b * NL_ * NP_;
    const float* Pr0 = Pb + (size_t)(r0 + 2*tr) * NP_;
    const float* Pr1 = Pr0 + NP_;

    // Q-phase: Q[l][4tc..] = sum_p P[l][p] * A[p][4tc..]
    const float4* A4 = (const float4*)A;
    float4 q0 = {0,0,0,0}, q1 = {0,0,0,0};
    #pragma unroll 8
    for (int p = 0; p < NP_; ++p) {
        float4 av = A4[p * 32 + tc];
        float pv0 = Pr0[p];
        float pv1 = Pr1[p];
        q0.x = fmaf(pv0, av.x, q0.x); q0.y = fmaf(pv0, av.y, q0.y);
        q0.z = fmaf(pv0, av.z, q0.z); q0.w = fmaf(pv0, av.w, q0.w);
        q1.x = fmaf(pv1, av.x, q1.x); q1.y = fmaf(pv1, av.y, q1.y);
        q1.z = fmaf(pv1, av.z, q1.z); q1.w = fmaf(pv1, av.w, q1.w);
    }

    // R-phase: R[l][4tc..] = sum_lp W[l][lp] * P[lp][4tc..]
    //          Wt[b][lp][i] with i = r0+2tr (+1) adjacent -> float2 broadcast.
    const float2* W2 = (const float2*)(Wt + (size_t)b * (NL_ * NL_));
    const float4* P4 = (const float4*)Pb;
    const int wof = (r0 >> 1) + tr;
    float4 ra0 = {0,0,0,0}, ra1 = {0,0,0,0};
    #pragma unroll 8
    for (int lp = 0; lp < NL_; ++lp) {
        float2 w01 = W2[lp * 64 + wof];
        float4 pv  = P4[lp * 32 + tc];
        ra0.x = fmaf(w01.x, pv.x, ra0.x); ra0.y = fmaf(w01.x, pv.y, ra0.y);
        ra0.z = fmaf(w01.x, pv.z, ra0.z); ra0.w = fmaf(w01.x, pv.w, ra0.w);
        ra1.x = fmaf(w01.y, pv.x, ra1.x); ra1.y = fmaf(w01.y, pv.y, ra1.y);
        ra1.z = fmaf(w01.y, pv.z, ra1.z); ra1.w = fmaf(w01.y, pv.w, ra1.w);
    }

    // partial num = <Q, R>
    float nacc = q0.x*ra0.x + q0.y*ra0.y + q0.z*ra0.z + q0.w*ra0.w
               + q1.x*ra1.x + q1.y*ra1.y + q1.z*ra1.z + q1.w*ra1.w;
    #pragma unroll
    for (int off = 32; off >= 1; off >>= 1) nacc += __shfl_xor(nacc, off, 64);
    __shared__ float red[4];
    if ((t & 63) == 0) red[t >> 6] = nacc;
    __syncthreads();
    if (t == 0) num_part[blockIdx.x] = red[0] + red[1] + red[2] + red[3];
}

// K3: loss = -(1/B) * sum_b (sum_c num[b,c]) / max(den[b], 1e-8)
__global__ __launch_bounds__(64) void k_final(
    const float* __restrict__ num_part,
    const float* __restrict__ den,
    float* __restrict__ out)
{
    int b = threadIdx.x;
    float n = 0.0f;
    #pragma unroll
    for (int c = 0; c < 8; ++c) n += num_part[b * 8 + c];
    float v = n / fmaxf(den[b], 1e-8f);
    #pragma unroll
    for (int off = 32; off >= 1; off >>= 1) v += __shfl_xor(v, off, 64);
    if (b == 0) out[0] = -v / (float)B_;
}

extern "C" void kernel_launch(void* const* d_in, const int* in_sizes, int n_in,
                              void* d_out, int out_size, void* d_ws, size_t ws_size,
                              hipStream_t stream) {
    const float* P       = (const float*)d_in[0];
    const float* d_error = (const float*)d_in[1];
    const float* ew      = (const float*)d_in[2];
    const int*   d_hw    = (const int*)d_in[3];
    const int*   pairs   = (const int*)d_in[4];
    float* out = (float*)d_out;

    char*  ws  = (char*)d_ws;
    float* Wt  = (float*)ws;
    float* den = (float*)(ws + 4194304);
    float* num = (float*)(ws + 4194560);
    float* A   = (float*)(ws + 4196608);

    // zero Wt + den (graph-capture-safe stream memset)
    hipMemsetAsync(ws, 0, 4194560, stream);

    k_prep <<<128, 256, 0, stream>>>(d_error, d_hw, ew, pairs, A, Wt, den);
    k_main <<<512, 256, 0, stream>>>(P, A, Wt, num);
    k_final<<<1,   64,  0, stream>>>(num, den, out);
}

// Round 6
// 99.627 us; speedup vs baseline: 1.0801x; 1.0801x over previous
//
#include <hip/hip_runtime.h>
#include <hip/hip_bf16.h>

#define B_   64
#define NL_  128
#define NP_  128
#define E_   4096

// ---------------------------------------------------------------------------
// Math: num[b] = <Q, R>,  Q = P[b]@A,  R = W[b]@P[b],
//       W[b][i][j] = sum of w_e over edges e=(i,j) of batch b.
//       den[b] = sum_e w_e;  loss = -(1/B) sum_b num[b]/max(den[b],1e-8)
//
// ws layout (bytes):
//   [0, 4194304)       Wt f32 [B][j=128][i=128]  (W transposed)
//   [4194304, +256)    den[64]
//   [4194560, +2048)   num_part[512]
//   [4196608, +65536)  A f32 [128][128]
// No memset needed: every region fully written before read, no atomics.
// ---------------------------------------------------------------------------

// K1: one block per batch. Builds A-chunk, den[b], and Wt[b] (LDS-built, then
// coalesced write). 64 blocks x 1024 threads.
__global__ __launch_bounds__(1024) void k_wbuild(
    const float* __restrict__ d_error,
    const int*   __restrict__ d_hw,
    const float* __restrict__ ew,
    const int*   __restrict__ pairs_raw,
    float* __restrict__ A,
    float* __restrict__ Wt,
    float* __restrict__ den)
{
    __shared__ float WT[NL_ * NL_];     // 64 KB, WT[j][i]
    __shared__ float rs[16];
    const int b = blockIdx.x;
    const int t = threadIdx.x;

    // zero W-slab (4 float4 per thread)
    float4* WT4 = (float4*)WT;
    #pragma unroll
    for (int k = 0; k < 4; ++k) WT4[k * 1024 + t] = float4{0, 0, 0, 0};

    // A chunk: 256 elements per block
    if (t < 256) {
        int idx = b * 256 + t;
        A[idx] = (d_hw[idx] == 1) ? fmaxf(1.0f - d_error[idx], 0.0f) : 0.0f;
    }

    // den[b]: 1024 threads x 1 float4 = 4096 weights
    const float* wrow = ew + (size_t)b * E_;
    {
        float4 v = ((const float4*)wrow)[t];
        float s = v.x + v.y + v.z + v.w;
        #pragma unroll
        for (int off = 32; off >= 1; off >>= 1) s += __shfl_xor(s, off, 64);
        if ((t & 63) == 0) rs[t >> 6] = s;
    }

    // int64-vs-int32 detection (same first-64 values in every wave)
    int hwv = pairs_raw[2 * (t & 63) + 1];
    unsigned long long nz = __ballot(hwv != 0);
    const int is64 = (nz == 0ULL);
    __syncthreads();

    if (t == 0) {
        float s = 0.0f;
        #pragma unroll
        for (int k = 0; k < 16; ++k) s += rs[k];
        den[b] = s;
    }

    // edge scatter into LDS: WT[j][i] += w   (4 edges per thread)
    if (is64) {
        const int4* pp = (const int4*)pairs_raw + (size_t)b * E_;
        #pragma unroll
        for (int k = 0; k < 4; ++k) {
            int e = k * 1024 + t;
            int4 pr = pp[e];
            atomicAdd(&WT[pr.z * NL_ + pr.x], wrow[e]);
        }
    } else {
        const int2* pp = (const int2*)pairs_raw + (size_t)b * E_;
        #pragma unroll
        for (int k = 0; k < 4; ++k) {
            int e = k * 1024 + t;
            int2 pr = pp[e];
            atomicAdd(&WT[pr.y * NL_ + pr.x], wrow[e]);
        }
    }
    __syncthreads();

    // coalesced write-out (4 float4 per thread)
    float4* Wg4 = (float4*)(Wt + (size_t)b * (NL_ * NL_));
    #pragma unroll
    for (int k = 0; k < 4; ++k) Wg4[k * 1024 + t] = WT4[k * 1024 + t];
}

// K2: LDS-free. 512 blocks = 64 batches x 8 row-chunks; 256 threads.
// Thread: rows r0+2tr, r0+2tr+1 (local), cols 4tc..4tc+3.
__global__ __launch_bounds__(256) void k_main(
    const float* __restrict__ P,
    const float* __restrict__ A,
    const float* __restrict__ Wt,
    float* __restrict__ num_part)
{
    const int b     = blockIdx.x >> 3;
    const int chunk = blockIdx.x & 7;
    const int r0    = chunk * 16;
    const int t  = threadIdx.x;
    const int tr = t >> 5;
    const int tc = t & 31;

    const float* Pb  = P + (size_t)b * NL_ * NP_;
    const float* Pr0 = Pb + (size_t)(r0 + 2*tr) * NP_;
    const float* Pr1 = Pr0 + NP_;

    // Q-phase: Q[l][4tc..] = sum_p P[l][p] * A[p][4tc..]
    const float4* A4 = (const float4*)A;
    float4 q0 = {0,0,0,0}, q1 = {0,0,0,0};
    #pragma unroll 8
    for (int p = 0; p < NP_; ++p) {
        float4 av = A4[p * 32 + tc];
        float pv0 = Pr0[p];
        float pv1 = Pr1[p];
        q0.x = fmaf(pv0, av.x, q0.x); q0.y = fmaf(pv0, av.y, q0.y);
        q0.z = fmaf(pv0, av.z, q0.z); q0.w = fmaf(pv0, av.w, q0.w);
        q1.x = fmaf(pv1, av.x, q1.x); q1.y = fmaf(pv1, av.y, q1.y);
        q1.z = fmaf(pv1, av.z, q1.z); q1.w = fmaf(pv1, av.w, q1.w);
    }

    // R-phase: R[l][4tc..] = sum_lp W[l][lp] * P[lp][4tc..]
    //          Wt[b][lp][i] with i = r0+2tr (+1) adjacent -> float2 broadcast.
    const float2* W2 = (const float2*)(Wt + (size_t)b * (NL_ * NL_));
    const float4* P4 = (const float4*)Pb;
    const int wof = (r0 >> 1) + tr;
    float4 ra0 = {0,0,0,0}, ra1 = {0,0,0,0};
    #pragma unroll 8
    for (int lp = 0; lp < NL_; ++lp) {
        float2 w01 = W2[lp * 64 + wof];
        float4 pv  = P4[lp * 32 + tc];
        ra0.x = fmaf(w01.x, pv.x, ra0.x); ra0.y = fmaf(w01.x, pv.y, ra0.y);
        ra0.z = fmaf(w01.x, pv.z, ra0.z); ra0.w = fmaf(w01.x, pv.w, ra0.w);
        ra1.x = fmaf(w01.y, pv.x, ra1.x); ra1.y = fmaf(w01.y, pv.y, ra1.y);
        ra1.z = fmaf(w01.y, pv.z, ra1.z); ra1.w = fmaf(w01.y, pv.w, ra1.w);
    }

    // partial num = <Q, R>
    float nacc = q0.x*ra0.x + q0.y*ra0.y + q0.z*ra0.z + q0.w*ra0.w
               + q1.x*ra1.x + q1.y*ra1.y + q1.z*ra1.z + q1.w*ra1.w;
    #pragma unroll
    for (int off = 32; off >= 1; off >>= 1) nacc += __shfl_xor(nacc, off, 64);
    __shared__ float red[4];
    if ((t & 63) == 0) red[t >> 6] = nacc;
    __syncthreads();
    if (t == 0) num_part[blockIdx.x] = red[0] + red[1] + red[2] + red[3];
}

// K3: loss = -(1/B) * sum_b (sum_c num[b,c]) / max(den[b], 1e-8)
__global__ __launch_bounds__(64) void k_final(
    const float* __restrict__ num_part,
    const float* __restrict__ den,
    float* __restrict__ out)
{
    int b = threadIdx.x;
    float n = 0.0f;
    #pragma unroll
    for (int c = 0; c < 8; ++c) n += num_part[b * 8 + c];
    float v = n / fmaxf(den[b], 1e-8f);
    #pragma unroll
    for (int off = 32; off >= 1; off >>= 1) v += __shfl_xor(v, off, 64);
    if (b == 0) out[0] = -v / (float)B_;
}

extern "C" void kernel_launch(void* const* d_in, const int* in_sizes, int n_in,
                              void* d_out, int out_size, void* d_ws, size_t ws_size,
                              hipStream_t stream) {
    const float* P       = (const float*)d_in[0];
    const float* d_error = (const float*)d_in[1];
    const float* ew      = (const float*)d_in[2];
    const int*   d_hw    = (const int*)d_in[3];
    const int*   pairs   = (const int*)d_in[4];
    float* out = (float*)d_out;

    char*  ws  = (char*)d_ws;
    float* Wt  = (float*)ws;
    float* den = (float*)(ws + 4194304);
    float* num = (float*)(ws + 4194560);
    float* A   = (float*)(ws + 4196608);

    k_wbuild<<<64,  1024, 0, stream>>>(d_error, d_hw, ew, pairs, A, Wt, den);
    k_main  <<<512, 256,  0, stream>>>(P, A, Wt, num);
    k_final <<<1,   64,   0, stream>>>(num, den, out);
}

// Round 7
// 95.909 us; speedup vs baseline: 1.1220x; 1.0388x over previous
//
#include <hip/hip_runtime.h>
#include <hip/hip_bf16.h>

#define B_   64
#define NL_  128
#define NP_  128
#define E_   4096

// ---------------------------------------------------------------------------
// Math: num[b] = <Q, R>,  Q = P[b]@A,  R = W[b]@P[b],
//       W[b][i][j] = sum of w_e over edges e=(i,j) of batch b.
//       den[b] = sum_e w_e;  loss = -(1/B) sum_b num[b]/max(den[b],1e-8)
//
// ws layout (bytes):
//   [0, 2048)         num_part[512]
//   [2048, +256)      den[64]
//   [4096, +65536)    A f32 [128][128]
// All regions fully written before read; no memset, no global atomics.
// ---------------------------------------------------------------------------

// K1: A build (256 elem/block) + den[b] (block b reduces its 4096 weights).
__global__ __launch_bounds__(256) void k_prep(
    const float* __restrict__ d_error,
    const int*   __restrict__ d_hw,
    const float* __restrict__ ew,
    float* __restrict__ A,
    float* __restrict__ den)
{
    const int b = blockIdx.x;           // 64 blocks
    const int t = threadIdx.x;

    int idx = b * 256 + t;
    A[idx] = (d_hw[idx] == 1) ? fmaxf(1.0f - d_error[idx], 0.0f) : 0.0f;

    const float4* ew4 = (const float4*)(ew + (size_t)b * E_);
    float s = 0.0f;
    #pragma unroll
    for (int k = 0; k < 4; ++k) {
        float4 v = ew4[k * 256 + t];
        s += v.x + v.y + v.z + v.w;
    }
    #pragma unroll
    for (int off = 32; off >= 1; off >>= 1) s += __shfl_xor(s, off, 64);
    __shared__ float rs[4];
    if ((t & 63) == 0) rs[t >> 6] = s;
    __syncthreads();
    if (t == 0) den[b] = rs[0] + rs[1] + rs[2] + rs[3];
}

// K2: 512 blocks = 64 batches x 8 row-chunks; 256 threads; 8 KB LDS.
// Per block: build 16-row W-slab in LDS (edge scan + LDS atomics, overlapped
// with the Q-phase's global-read GEMM), then R-phase GEMM + <Q,R> partial.
// Thread: local rows 2tr, 2tr+1; cols 4tc..4tc+3.
__global__ __launch_bounds__(256) void k_main(
    const float* __restrict__ P,
    const float* __restrict__ A,
    const float* __restrict__ ew,
    const int*   __restrict__ pairs_raw,
    float* __restrict__ num_part)
{
    __shared__ float WT[NL_ * 16];      // WT[j][i_local] = W[r0+i_local][j]
    __shared__ float red[4];

    const int b     = blockIdx.x >> 3;
    const int chunk = blockIdx.x & 7;
    const int r0    = chunk * 16;
    const int t  = threadIdx.x;
    const int tr = t >> 5;              // 0..7 -> local rows 2tr, 2tr+1
    const int tc = t & 31;              // cols 4tc..4tc+3

    // zero W-slab (2 float4 per thread)
    float4* WT4 = (float4*)WT;
    WT4[2*t]     = float4{0,0,0,0};
    WT4[2*t + 1] = float4{0,0,0,0};

    // int64-vs-int32 detection: high words of first 64 values all zero <=> int64
    int hwv = pairs_raw[2 * (t & 63) + 1];
    unsigned long long nz = __ballot(hwv != 0);
    const int is64 = (nz == 0ULL);
    __syncthreads();                    // slab zeroed before atomics

    // edge scan + scatter into LDS slab (16 edges/thread)
    const float* wrow = ew + (size_t)b * E_;
    if (is64) {
        const int4* pp = (const int4*)pairs_raw + (size_t)b * E_;
        #pragma unroll 4
        for (int k = 0; k < 16; ++k) {
            int e = k * 256 + t;
            int4 pr = pp[e];
            if (pr.x >= r0 && pr.x < r0 + 16)
                atomicAdd(&WT[pr.z * 16 + (pr.x - r0)], wrow[e]);
        }
    } else {
        const int2* pp = (const int2*)pairs_raw + (size_t)b * E_;
        #pragma unroll 4
        for (int k = 0; k < 16; ++k) {
            int e = k * 256 + t;
            int2 pr = pp[e];
            if (pr.x >= r0 && pr.x < r0 + 16)
                atomicAdd(&WT[pr.y * 16 + (pr.x - r0)], wrow[e]);
        }
    }

    // Q-phase (global-only; overlaps LDS-atomic drain):
    const float* Pb  = P + (size_t)b * NL_ * NP_;
    const float* Pr0 = Pb + (size_t)(r0 + 2*tr) * NP_;
    const float* Pr1 = Pr0 + NP_;
    const float4* A4 = (const float4*)A;
    float4 q0 = {0,0,0,0}, q1 = {0,0,0,0};
    #pragma unroll 8
    for (int p = 0; p < NP_; ++p) {
        float4 av = A4[p * 32 + tc];
        float pv0 = Pr0[p];
        float pv1 = Pr1[p];
        q0.x = fmaf(pv0, av.x, q0.x); q0.y = fmaf(pv0, av.y, q0.y);
        q0.z = fmaf(pv0, av.z, q0.z); q0.w = fmaf(pv0, av.w, q0.w);
        q1.x = fmaf(pv1, av.x, q1.x); q1.y = fmaf(pv1, av.y, q1.y);
        q1.z = fmaf(pv1, av.z, q1.z); q1.w = fmaf(pv1, av.w, q1.w);
    }
    __syncthreads();                    // slab complete

    // R-phase: R[l][4tc..] = sum_lp W[l][lp] * P[lp][4tc..]
    // W from LDS (float2 broadcast per 32-lane group), P via L1/L2.
    const float2* WT2 = (const float2*)WT;
    const float4* P4  = (const float4*)Pb;
    float4 ra0 = {0,0,0,0}, ra1 = {0,0,0,0};
    #pragma unroll 8
    for (int lp = 0; lp < NL_; ++lp) {
        float2 w01 = WT2[lp * 8 + tr];  // W[r0+2tr][lp], W[r0+2tr+1][lp]
        float4 pv  = P4[lp * 32 + tc];
        ra0.x = fmaf(w01.x, pv.x, ra0.x); ra0.y = fmaf(w01.x, pv.y, ra0.y);
        ra0.z = fmaf(w01.x, pv.z, ra0.z); ra0.w = fmaf(w01.x, pv.w, ra0.w);
        ra1.x = fmaf(w01.y, pv.x, ra1.x); ra1.y = fmaf(w01.y, pv.y, ra1.y);
        ra1.z = fmaf(w01.y, pv.z, ra1.z); ra1.w = fmaf(w01.y, pv.w, ra1.w);
    }

    // partial num = <Q, R>
    float nacc = q0.x*ra0.x + q0.y*ra0.y + q0.z*ra0.z + q0.w*ra0.w
               + q1.x*ra1.x + q1.y*ra1.y + q1.z*ra1.z + q1.w*ra1.w;
    #pragma unroll
    for (int off = 32; off >= 1; off >>= 1) nacc += __shfl_xor(nacc, off, 64);
    if ((t & 63) == 0) red[t >> 6] = nacc;
    __syncthreads();
    if (t == 0) num_part[blockIdx.x] = red[0] + red[1] + red[2] + red[3];
}

// K3: loss = -(1/B) * sum_b (sum_c num[b,c]) / max(den[b], 1e-8)
__global__ __launch_bounds__(64) void k_final(
    const float* __restrict__ num_part,
    const float* __restrict__ den,
    float* __restrict__ out)
{
    int b = threadIdx.x;
    float n = 0.0f;
    #pragma unroll
    for (int c = 0; c < 8; ++c) n += num_part[b * 8 + c];
    float v = n / fmaxf(den[b], 1e-8f);
    #pragma unroll
    for (int off = 32; off >= 1; off >>= 1) v += __shfl_xor(v, off, 64);
    if (b == 0) out[0] = -v / (float)B_;
}

extern "C" void kernel_launch(void* const* d_in, const int* in_sizes, int n_in,
                              void* d_out, int out_size, void* d_ws, size_t ws_size,
                              hipStream_t stream) {
    const float* P       = (const float*)d_in[0];
    const float* d_error = (const float*)d_in[1];
    const float* ew      = (const float*)d_in[2];
    const int*   d_hw    = (const int*)d_in[3];
    const int*   pairs   = (const int*)d_in[4];
    float* out = (float*)d_out;

    char*  ws  = (char*)d_ws;
    float* num = (float*)ws;
    float* den = (float*)(ws + 2048);
    float* A   = (float*)(ws + 4096);

    k_prep <<<64,  256, 0, stream>>>(d_error, d_hw, ew, A, den);
    k_main <<<512, 256, 0, stream>>>(P, A, ew, pairs, num);
    k_final<<<1,   64,  0, stream>>>(num, den, out);
}